// Round 3
// baseline (133.025 us; speedup 1.0000x reference)
//
#include <hip/hip_runtime.h>
#include <math.h>

// SE block: x[32,512,56,56] fp32
//   squeeze = mean over (H,W) -> [32,512]
//   h = relu(squeeze @ w1^T + b1)      w1: [32,512]
//   e = sigmoid(h @ w2^T + b2)         w2: [512,32]
//   out = x * e[b,c] broadcast
//
// Memory-bound. Strategy: squeeze reads fp32 x once (unavoidable 205 MB) and
// simultaneously writes an fp16 shadow copy x~ (103 MB) to workspace with
// allocating stores (L3-resident). Scale reads x~ (half the bytes, L3-served)
// and nt-stores fp32 out (205 MB, no cache pollution). fp16 adds <=0.003
// absmax error vs 0.0575 threshold.

#define SE_C 512
#define SE_CR 32
#define SE_B 32
#define SPATIAL 3136            // 56*56
#define VEC_PER_ROW 784         // float4s per row
#define H8_PER_ROW 392          // half8s per row

typedef float f4 __attribute__((ext_vector_type(4)));
typedef _Float16 h4 __attribute__((ext_vector_type(4)));
typedef _Float16 h8 __attribute__((ext_vector_type(8)));

// ---------------- Kernel 1: squeeze + fp16 shadow cast ----------------
__global__ __launch_bounds__(256) void se_squeeze_cast(const f4* __restrict__ x,
                                                       h4* __restrict__ xh,
                                                       float* __restrict__ sq) {
    const int row = blockIdx.x;
    const f4* p = x + (size_t)row * VEC_PER_ROW;
    h4* q = xh + (size_t)row * VEC_PER_ROW;
    float s = 0.f;
    for (int i = threadIdx.x; i < VEC_PER_ROW; i += 256) {
        f4 v = p[i];
        s += (v.x + v.y) + (v.z + v.w);
        h4 h;
        h.x = (_Float16)v.x; h.y = (_Float16)v.y;
        h.z = (_Float16)v.z; h.w = (_Float16)v.w;
        q[i] = h;                                // allocating store -> L3
    }
    #pragma unroll
    for (int off = 32; off > 0; off >>= 1) s += __shfl_down(s, off, 64);
    __shared__ float wsum[4];
    const int wave = threadIdx.x >> 6;
    if ((threadIdx.x & 63) == 0) wsum[wave] = s;
    __syncthreads();
    if (threadIdx.x == 0) {
        float t = (wsum[0] + wsum[1]) + (wsum[2] + wsum[3]);
        sq[row] = t * (1.0f / (float)SPATIAL);
    }
}

// plain squeeze (fallback when ws too small for the shadow copy)
__global__ __launch_bounds__(256) void se_squeeze(const f4* __restrict__ x,
                                                  float* __restrict__ sq) {
    const int row = blockIdx.x;
    const f4* p = x + (size_t)row * VEC_PER_ROW;
    float s = 0.f;
    for (int i = threadIdx.x; i < VEC_PER_ROW; i += 256) {
        f4 v = p[i];
        s += (v.x + v.y) + (v.z + v.w);
    }
    #pragma unroll
    for (int off = 32; off > 0; off >>= 1) s += __shfl_down(s, off, 64);
    __shared__ float wsum[4];
    const int wave = threadIdx.x >> 6;
    if ((threadIdx.x & 63) == 0) wsum[wave] = s;
    __syncthreads();
    if (threadIdx.x == 0) {
        float t = (wsum[0] + wsum[1]) + (wsum[2] + wsum[3]);
        sq[row] = t * (1.0f / (float)SPATIAL);
    }
}

// ---------------- Kernel 2: excitation (two tiny FCs) ----------------
__global__ __launch_bounds__(512) void se_excite(const float* __restrict__ sq,
                                                 const float* __restrict__ w1,
                                                 const float* __restrict__ b1,
                                                 const float* __restrict__ w2,
                                                 const float* __restrict__ b2,
                                                 float* __restrict__ e) {
    const int b = blockIdx.x;
    __shared__ float s_lds[SE_C];
    __shared__ float h_lds[SE_CR];
    const int t = threadIdx.x;
    s_lds[t] = sq[b * SE_C + t];
    __syncthreads();
    if (t < SE_CR) {
        float acc = b1[t];
        const float* wr = w1 + t * SE_C;
        for (int c = 0; c < SE_C; ++c) acc += s_lds[c] * wr[c];
        h_lds[t] = fmaxf(acc, 0.f);
    }
    __syncthreads();
    {
        float acc = b2[t];
        const float* wr = w2 + t * SE_CR;
        #pragma unroll
        for (int j = 0; j < SE_CR; ++j) acc += h_lds[j] * wr[j];
        e[b * SE_C + t] = 1.0f / (1.0f + expf(-acc));
    }
}

// ---------------- Kernel 3: scale from fp16 shadow ----------------
__global__ __launch_bounds__(256) void se_scale_h(const h8* __restrict__ xh,
                                                  const float* __restrict__ e,
                                                  f4* __restrict__ out) {
    const int row = blockIdx.x;
    const float s = e[row];
    const h8* px = xh + (size_t)row * H8_PER_ROW;
    f4* po = out + (size_t)row * VEC_PER_ROW;
    for (int i = threadIdx.x; i < H8_PER_ROW; i += 256) {
        h8 v = px[i];
        f4 a, b;
        a.x = (float)v[0] * s; a.y = (float)v[1] * s;
        a.z = (float)v[2] * s; a.w = (float)v[3] * s;
        b.x = (float)v[4] * s; b.y = (float)v[5] * s;
        b.z = (float)v[6] * s; b.w = (float)v[7] * s;
        __builtin_nontemporal_store(a, po + 2 * i);
        __builtin_nontemporal_store(b, po + 2 * i + 1);
    }
}

// fp32 scale (fallback)
__global__ __launch_bounds__(256) void se_scale(const f4* __restrict__ x,
                                                const float* __restrict__ e,
                                                f4* __restrict__ out) {
    const int row = blockIdx.x;
    const float s = e[row];
    const f4* px = x + (size_t)row * VEC_PER_ROW;
    f4* po = out + (size_t)row * VEC_PER_ROW;
    for (int i = threadIdx.x; i < VEC_PER_ROW; i += 256) {
        f4 v = px[i];
        f4 o = v * s;
        __builtin_nontemporal_store(o, po + i);
    }
}

extern "C" void kernel_launch(void* const* d_in, const int* in_sizes, int n_in,
                              void* d_out, int out_size, void* d_ws, size_t ws_size,
                              hipStream_t stream) {
    const float* x  = (const float*)d_in[0];
    const float* w1 = (const float*)d_in[1];
    const float* b1 = (const float*)d_in[2];
    const float* w2 = (const float*)d_in[3];
    const float* b2 = (const float*)d_in[4];
    float* out = (float*)d_out;

    const int rows = SE_B * SE_C;                       // 16384
    float* sq = (float*)d_ws;                           // [16384]
    float* e  = sq + rows;                              // [16384]
    h4*    xh = (h4*)(e + rows);                        // [rows * 784] h4

    const size_t need = 2ull * rows * sizeof(float)
                      + (size_t)rows * SPATIAL * sizeof(_Float16);

    if (ws_size >= need) {
        se_squeeze_cast<<<rows, 256, 0, stream>>>((const f4*)x, xh, sq);
        se_excite<<<SE_B, 512, 0, stream>>>(sq, w1, b1, w2, b2, e);
        se_scale_h<<<rows, 256, 0, stream>>>((const h8*)xh, e, (f4*)out);
    } else {
        se_squeeze<<<rows, 256, 0, stream>>>((const f4*)x, sq);
        se_excite<<<SE_B, 512, 0, stream>>>(sq, w1, b1, w2, b2, e);
        se_scale<<<rows, 256, 0, stream>>>((const f4*)x, e, (f4*)out);
    }
}

// Round 4
// 107.747 us; speedup vs baseline: 1.2346x; 1.2346x over previous
//
#include <hip/hip_runtime.h>
#include <math.h>

// SE block: x[32,512,56,56] fp32
//   squeeze = mean over (H,W) -> [32,512]
//   h = relu(squeeze @ w1^T + b1)      w1: [32,512]
//   e = sigmoid(h @ w2^T + b2)         w2: [512,32]
//   out = x * e[b,c] broadcast
//
// Memory-bound: 615 MB/replay (read x twice + write out) @ ~7.1 TB/s ≈ 87 us.
// fp16-shadow experiment (round 3) proved L3 gives no free streaming re-reads:
// all bytes price at HBM rate. So: minimize bytes (615 is the floor without
// precision tricks that round 3 showed don't pay) and maximize stream quality.
// Wave-per-row structure: no LDS, no syncthreads, full unroll -> deep MLP.

#define SE_C 512
#define SE_CR 32
#define SE_B 32
#define SPATIAL 3136            // 56*56
#define VEC_PER_ROW 784         // float4s per (b,c) row
#define ROWS (SE_B * SE_C)      // 16384

typedef float f4 __attribute__((ext_vector_type(4)));

// ---------------- Kernel 1: global average pool ----------------
// 2048 blocks x 4 waves; each wave reduces 2 full rows with shuffle only.
__global__ __launch_bounds__(256) void se_squeeze(const f4* __restrict__ x,
                                                  float* __restrict__ sq) {
    const int wave = threadIdx.x >> 6;
    const int lane = threadIdx.x & 63;
    const int base = blockIdx.x * 8 + wave * 2;   // 2 rows per wave
    #pragma unroll
    for (int sub = 0; sub < 2; ++sub) {
        const int row = base + sub;
        const f4* p = x + (size_t)row * VEC_PER_ROW;
        float s = 0.f;
        #pragma unroll
        for (int k = 0; k < 13; ++k) {            // 13*64 = 832 >= 784
            const int i = lane + (k << 6);
            if (i < VEC_PER_ROW) {
                f4 v = p[i];
                s += (v.x + v.y) + (v.z + v.w);
            }
        }
        #pragma unroll
        for (int off = 32; off > 0; off >>= 1) s += __shfl_down(s, off, 64);
        if (lane == 0) sq[row] = s * (1.0f / (float)SPATIAL);
    }
}

// ---------------- Kernel 2: excitation (two tiny FCs) ----------------
__global__ __launch_bounds__(512) void se_excite(const float* __restrict__ sq,
                                                 const float* __restrict__ w1,
                                                 const float* __restrict__ b1,
                                                 const float* __restrict__ w2,
                                                 const float* __restrict__ b2,
                                                 float* __restrict__ e) {
    const int b = blockIdx.x;
    __shared__ float s_lds[SE_C];
    __shared__ float h_lds[SE_CR];
    const int t = threadIdx.x;
    s_lds[t] = sq[b * SE_C + t];
    __syncthreads();
    if (t < SE_CR) {
        float acc = b1[t];
        const float* wr = w1 + t * SE_C;
        for (int c = 0; c < SE_C; ++c) acc += s_lds[c] * wr[c];
        h_lds[t] = fmaxf(acc, 0.f);
    }
    __syncthreads();
    {
        float acc = b2[t];
        const float* wr = w2 + t * SE_CR;
        #pragma unroll
        for (int j = 0; j < SE_CR; ++j) acc += h_lds[j] * wr[j];
        e[b * SE_C + t] = 1.0f / (1.0f + expf(-acc));
    }
}

// ---------------- Kernel 3: broadcast scale ----------------
// 2048 blocks x 4 waves; each wave scales 2 rows. NT loads (single-use x,
// don't thrash L2 against the store stream) + NT stores (out never re-read).
__global__ __launch_bounds__(256) void se_scale(const f4* __restrict__ x,
                                                const float* __restrict__ e,
                                                f4* __restrict__ out) {
    const int wave = threadIdx.x >> 6;
    const int lane = threadIdx.x & 63;
    const int base = blockIdx.x * 8 + wave * 2;
    #pragma unroll
    for (int sub = 0; sub < 2; ++sub) {
        const int row = base + sub;
        const float s = e[row];
        const f4* px = x + (size_t)row * VEC_PER_ROW;
        f4* po = out + (size_t)row * VEC_PER_ROW;
        #pragma unroll
        for (int k = 0; k < 13; ++k) {
            const int i = lane + (k << 6);
            if (i < VEC_PER_ROW) {
                f4 v = __builtin_nontemporal_load(px + i);
                __builtin_nontemporal_store(v * s, po + i);
            }
        }
    }
}

extern "C" void kernel_launch(void* const* d_in, const int* in_sizes, int n_in,
                              void* d_out, int out_size, void* d_ws, size_t ws_size,
                              hipStream_t stream) {
    const float* x  = (const float*)d_in[0];
    const float* w1 = (const float*)d_in[1];
    const float* b1 = (const float*)d_in[2];
    const float* w2 = (const float*)d_in[3];
    const float* b2 = (const float*)d_in[4];
    float* out = (float*)d_out;

    float* sq = (float*)d_ws;                 // [16384]
    float* e  = sq + ROWS;                    // [16384]

    se_squeeze<<<ROWS / 8, 256, 0, stream>>>((const f4*)x, sq);
    se_excite<<<SE_B, 512, 0, stream>>>(sq, w1, b1, w2, b2, e);
    se_scale<<<ROWS / 8, 256, 0, stream>>>((const f4*)x, e, (f4*)out);
}